// Round 8
// baseline (260.603 us; speedup 1.0000x reference)
//
#include <hip/hip_runtime.h>
#include <cstdint>
#include <cstddef>

// ConcreteLayer forward: out = x @ softmax_rows((W + gumbel(U))/T)
// Reformulation v2 (dependency-broken):
//   e[i,k]   = exp((W+G)/T)          (stored bf16, UNSCALED, transposed -> BT [OUT,IN])
//   dpart[t,i] = partial row sums of e over OUT-tile t   (non-atomic, exclusive writes)
//   bt_scale:  BT[k,i] *= 1/sum_t dpart[t,i]             (16 MB pass)
//   out = bf16(x) @ BT                                   (no-LDS register MFMA GEMM, split-K=2)
// B=4096, IN=4096, OUT=1024.
// ws: xb (bf16 x, 32MB) | bt (bf16 e^T [OUT,IN], 8MB) | dpart ([16][4096] f32, 256KB)
//
// GEMM history: 128x128 LDS 2blk/CU = 505 TF (R0); split-K4 (R1) -2x atomics regress;
// 2-phase dbuf (R2) neutral; 8-phase 256^2 (R4/R5) 3x regress; 128x64 LDS 4blk/CU (R6)
// = 557 TF. R7 model: the LDS structure is LDS-PIPE-bound (~43us/CU of ds traffic vs
// ~4us MFMA) - scheduling can't fix a saturated pipe. R8: remove LDS entirely. Both
// xb and BT are K-major -> MFMA fragments are 16B-contiguous GLOBAL reads (16 rows x
// 64B full cachelines per load instr). Working set L2/L3-resident; natural grid order
// co-locates each A-panel's 16 consumer blocks on one XCD (linear id = x mod 8).
// Register dbuf across K-tiles (static indices only), no barriers at all.

#define TINYF 1.17549435082228750797e-38f
#define LN2F 0.69314718055994530942f
#define LOG2EF 1.44269504088896340736f

typedef unsigned short u16;
typedef __attribute__((ext_vector_type(8))) short bf16x8;
typedef __attribute__((ext_vector_type(4))) float f32x4;

__device__ __forceinline__ u16 f2bf(float f) {
  union { float f; uint32_t u; } v; v.f = f;
  uint32_t r = v.u + 0x7FFFu + ((v.u >> 16) & 1u);  // RNE
  return (u16)(r >> 16);
}
__device__ __forceinline__ float bf2f(u16 h) {
  union { float f; uint32_t u; } v; v.u = ((uint32_t)h) << 16;
  return v.f;
}

__device__ __forceinline__ float log2_hw(float x) { return __builtin_amdgcn_logf(x); }
__device__ __forceinline__ float exp2_hw(float x) { return __builtin_amdgcn_exp2f(x); }

// g = -ln(-ln(u)) = -ln2 * log2(ln2 * (-log2 u))
__device__ __forceinline__ float gumbel_fast(float u) {
  float t = -log2_hw(u);
  return -LN2F * log2_hw(t * LN2F);
}
__device__ __forceinline__ float exp_fast(float x) { return exp2_hw(x * LOG2EF); }

// ---------------- kernel 1: fused prep (exact R6 form) ----------------
// blocks [0, 1024): 64x64 exp-transpose tiles of l -> BT (unscaled) + dpart sums
// blocks [1024, 1024+16384): x f32 -> bf16 cast (no scaling)
// blocks [1024+16384, +4096): zero out (split-K accumulator)
#define NB_TRANS 1024
#define NB_CAST 16384
#define NB_ZERO 4096

__global__ void prep_kernel(const float* __restrict__ W, const float* __restrict__ U,
                            const float* __restrict__ Tp, const float4* __restrict__ x,
                            u16* __restrict__ BT, float* __restrict__ dpart,
                            ushort4* __restrict__ xb, float4* __restrict__ out) {
  __shared__ float tile[64][65];
  const int bx = blockIdx.x;
  const int t = threadIdx.x;

  if (bx < NB_TRANS) {
    // ---- exp-transpose tile: k0 = IN-row tile (64 of them), n0 = OUT-col tile (16)
    const int k0 = (bx & 63) * 64, n0 = (bx >> 6) * 64;
    const float invT = 1.0f / Tp[0];
    {
      const int nn4 = (t & 15) * 4, kq = t >> 4;  // 16 rows per pass, float4 cols
#pragma unroll
      for (int r = 0; r < 4; ++r) {
        int kk = r * 16 + kq;
        size_t gi = (size_t)(k0 + kk) * 1024 + (n0 + nn4);
        float4 w = *(const float4*)&W[gi];
        float4 u = *(const float4*)&U[gi];
        float e0 = exp_fast((w.x + gumbel_fast(u.x * (1.0f - TINYF) + TINYF)) * invT);
        float e1 = exp_fast((w.y + gumbel_fast(u.y * (1.0f - TINYF) + TINYF)) * invT);
        float e2 = exp_fast((w.z + gumbel_fast(u.z * (1.0f - TINYF) + TINYF)) * invT);
        float e3 = exp_fast((w.w + gumbel_fast(u.w * (1.0f - TINYF) + TINYF)) * invT);
        tile[kk][nn4 + 0] = e0; tile[kk][nn4 + 1] = e1;
        tile[kk][nn4 + 2] = e2; tile[kk][nn4 + 3] = e3;
        // partial row sum over this thread's 4 cols; reduce across 16 lanes sharing kk
        float s = (e0 + e1) + (e2 + e3);
#pragma unroll
        for (int m = 8; m > 0; m >>= 1) s += __shfl_xor(s, m, 16);
        // exclusive (n-tile, row) slot: no atomics, no pre-zeroing needed
        if ((t & 15) == 0) dpart[(bx >> 6) * 4096 + k0 + kk] = s;
      }
    }
    __syncthreads();
    {
      const int kk4 = (t & 15) * 4, nq = t >> 4;
#pragma unroll
      for (int r = 0; r < 4; ++r) {
        int nn = r * 16 + nq;
        ushort4 o;
        o.x = f2bf(tile[kk4 + 0][nn]);
        o.y = f2bf(tile[kk4 + 1][nn]);
        o.z = f2bf(tile[kk4 + 2][nn]);
        o.w = f2bf(tile[kk4 + 3][nn]);
        *(ushort4*)&BT[(size_t)(n0 + nn) * 4096 + (k0 + kk4)] = o;
      }
    }
  } else if (bx < NB_TRANS + NB_CAST) {
    // ---- x f32 -> bf16 (unscaled; 1/d lives on the BT side)
    int i = (bx - NB_TRANS) * 256 + t;
    float4 v = x[i];
    ushort4 o;
    o.x = f2bf(v.x); o.y = f2bf(v.y); o.z = f2bf(v.z); o.w = f2bf(v.w);
    xb[i] = o;
  } else {
    // ---- zero split-K accumulator
    int j = (bx - NB_TRANS - NB_CAST) * 256 + t;
    out[j] = make_float4(0.f, 0.f, 0.f, 0.f);
  }
}

// ---------------- kernel 2: BT[k,i] *= 1/d_i ----------------
__global__ void bt_scale_kernel(u16* __restrict__ BT, const float* __restrict__ dpart) {
  __shared__ float invd[128];
  const int c0 = blockIdx.x * 128;  // IN col tile (32)
  const int r0 = blockIdx.y * 128;  // OUT row tile (8)
  const int t = threadIdx.x;
  if (t < 128) {
    float s = 0.f;
#pragma unroll
    for (int p = 0; p < 16; ++p) s += dpart[p * 4096 + c0 + t];
    invd[t] = 1.0f / s;
  }
  __syncthreads();
  const int cv = (t & 15) * 8, rq = t >> 4;
  const float4 ia = *(const float4*)&invd[cv];
  const float4 ib = *(const float4*)&invd[cv + 4];
#pragma unroll
  for (int pass = 0; pass < 8; ++pass) {
    int row = r0 + pass * 16 + rq;
    size_t gi = (size_t)row * 4096 + c0 + cv;
    ushort4 a = *(ushort4*)&BT[gi];
    ushort4 b = *(ushort4*)&BT[gi + 4];
    ushort4 oa, ob;
    oa.x = f2bf(bf2f(a.x) * ia.x); oa.y = f2bf(bf2f(a.y) * ia.y);
    oa.z = f2bf(bf2f(a.z) * ia.z); oa.w = f2bf(bf2f(a.w) * ia.w);
    ob.x = f2bf(bf2f(b.x) * ib.x); ob.y = f2bf(bf2f(b.y) * ib.y);
    ob.z = f2bf(bf2f(b.z) * ib.z); ob.w = f2bf(bf2f(b.w) * ib.w);
    *(ushort4*)&BT[gi] = oa;
    *(ushort4*)&BT[gi + 4] = ob;
  }
}

// ---------------- kernel 3: no-LDS register GEMM, 128x128 block, split-K=2 ----------------
// 4 waves (2x2), per-wave 64x64, acc 4x4 f32x4 = 64 regs. Fragments loaded DIRECTLY
// from global: per load instr, 16 lanes-rows x 64B contiguous (4 quads x 16B) = full
// cachelines. K-tile (64 elem) register double-buffer: load tile t+1 while computing
// tile t (32 MFMA of cover per 16-load burst). All frag indices compile-time (SROA).
// Numerics: identical MFMA order to R6 -> bit-identical output.
#define TM 128
#define TN 128
#define SPLITK 2

__launch_bounds__(256, 2)
__global__ void gemm_bt_kernel(const u16* __restrict__ A, const u16* __restrict__ BT,
                               float* __restrict__ C, int M, int N, int K) {
  const int tid = threadIdx.x;
  const int lane = tid & 63, w = tid >> 6;
  const int wm = w >> 1, wn = w & 1;           // 2x2 wave grid, 64x64 per wave
  const int m0 = blockIdx.x * TM, n0 = blockIdx.y * TN;
  const int quad = lane >> 4, r16 = lane & 15;

  const int kz = blockIdx.z;                   // split-K = 2
  const int Kh = K >> 1;
  const u16* Ak = A + (size_t)kz * Kh;
  const u16* Bk = BT + (size_t)kz * Kh;

  // per-lane fragment base pointers: row-major K-major; element k = t*64 + s2*32 + quad*8
  const u16* ap[4];
  const u16* bp[4];
#pragma unroll
  for (int i = 0; i < 4; ++i) {
    ap[i] = Ak + (size_t)(m0 + wm * 64 + i * 16 + r16) * K + quad * 8;
    bp[i] = Bk + (size_t)(n0 + wn * 64 + i * 16 + r16) * K + quad * 8;
  }

  f32x4 acc[4][4] = {};
  bf16x8 aF[2][2][4], bF[2][2][4];  // [buf][substep][frag] - all indices compile-time

#define LDT(BUF, T)                                                                \
  {                                                                                \
    _Pragma("unroll") for (int s2 = 0; s2 < 2; ++s2) {                             \
      _Pragma("unroll") for (int i = 0; i < 4; ++i) {                              \
        aF[BUF][s2][i] = *(const bf16x8*)(ap[i] + (size_t)(T) * 64 + s2 * 32);     \
        bF[BUF][s2][i] = *(const bf16x8*)(bp[i] + (size_t)(T) * 64 + s2 * 32);     \
      }                                                                            \
    }                                                                              \
  }
#define FMT(BUF)                                                                   \
  {                                                                                \
    _Pragma("unroll") for (int s2 = 0; s2 < 2; ++s2)                               \
      _Pragma("unroll") for (int mi = 0; mi < 4; ++mi)                             \
        _Pragma("unroll") for (int ni = 0; ni < 4; ++ni)                           \
          acc[mi][ni] = __builtin_amdgcn_mfma_f32_16x16x32_bf16(                   \
              aF[BUF][s2][mi], bF[BUF][s2][ni], acc[mi][ni], 0, 0, 0);             \
  }

  const int NTL = Kh / 64;  // 32 K-tiles
  LDT(0, 0)
  for (int t = 0; t + 2 < NTL; t += 2) {
    LDT(1, t + 1)
    FMT(0)
    LDT(0, t + 2)
    FMT(1)
  }
  LDT(1, NTL - 1)
  FMT(0)
  FMT(1)
#undef LDT
#undef FMT

  // epilogue: C/D layout col = lane&15, row = quad*4 + reg
#pragma unroll
  for (int mi = 0; mi < 4; ++mi)
#pragma unroll
    for (int ni = 0; ni < 4; ++ni)
#pragma unroll
      for (int r = 0; r < 4; ++r) {
        int row = m0 + wm * 64 + mi * 16 + quad * 4 + r;
        int col = n0 + wn * 64 + ni * 16 + r16;
        atomicAdd(&C[(size_t)row * N + col], acc[mi][ni][r]);
      }
}

extern "C" void kernel_launch(void* const* d_in, const int* in_sizes, int n_in,
                              void* d_out, int out_size, void* d_ws, size_t ws_size,
                              hipStream_t stream) {
  const int M = 4096, K = 4096, N = 1024;  // B, IN, OUT
  const float* x = (const float*)d_in[0];
  const float* W = (const float*)d_in[1];
  const float* U = (const float*)d_in[2];
  const float* Tp = (const float*)d_in[3];
  float* out = (float*)d_out;

  char* ws = (char*)d_ws;
  u16* xb = (u16*)ws;                                          // 32 MB
  u16* bt = (u16*)(ws + (size_t)M * K * 2);                    // 8 MB
  float* dpart = (float*)(ws + (size_t)M * K * 2 + (size_t)N * K * 2);  // 256 KB

  prep_kernel<<<dim3(NB_TRANS + NB_CAST + NB_ZERO), 256, 0, stream>>>(
      W, U, Tp, (const float4*)x, bt, dpart, (ushort4*)xb, (float4*)out);
  bt_scale_kernel<<<dim3(32, 8), 256, 0, stream>>>(bt, dpart);
  gemm_bt_kernel<<<dim3(M / TM, N / TN, SPLITK), 256, 0, stream>>>(xb, bt, out, M, N, K);
}